// Round 1
// baseline (312.612 us; speedup 1.0000x reference)
//
#include <hip/hip_runtime.h>
#include <hip/hip_bf16.h>

#define NH 4
#define HD 64
#define HID 256
#define BB 2
#define SS 4096

typedef float f4 __attribute__((ext_vector_type(4)));
typedef short bf8v __attribute__((ext_vector_type(8)));   // 8 bf16 (4 VGPRs)
typedef unsigned int u4v __attribute__((ext_vector_type(4)));

// ---------------------------------------------------------------------------
// QKV projection: X(8192x256) @ W^T + b for wq/wk/wv.
// q,k stored bf16 [b][h][s][d]; v stored bf16 TRANSPOSED [b][h][d][s].
// grid (12, 128), block 256. blockIdx.x: 4 n-tiles per projection x 3 projs.
// ---------------------------------------------------------------------------
__global__ __launch_bounds__(256)
void qkv_proj_kernel(const float* __restrict__ x,
                     const float* __restrict__ wq, const float* __restrict__ bq,
                     const float* __restrict__ wk, const float* __restrict__ bk,
                     const float* __restrict__ wv, const float* __restrict__ bv,
                     __hip_bfloat16* __restrict__ qb,
                     __hip_bfloat16* __restrict__ kb,
                     __hip_bfloat16* __restrict__ vtb)
{
    const int nt = blockIdx.x;            // 0..11
    const int m0 = blockIdx.y * 64;       // row tile
    const int proj = nt >> 2;             // 0=q 1=k 2=v
    const int n0 = (nt & 3) * 64;         // col within projection (0..255)
    const float* __restrict__ w  = (proj == 0) ? wq : (proj == 1) ? wk : wv;
    const float* __restrict__ bs = (proj == 0) ? bq : (proj == 1) ? bk : bv;

    __shared__ __align__(16) float xs[64][68];   // [row][k], pad to 68 (2-way max)
    __shared__ __align__(16) float wt[64][64];   // [k][col] (transposed stage)

    const int tid = threadIdx.x;
    const int tx = tid & 15, ty = tid >> 4;

    float acc[4][4] = {};

    for (int k0 = 0; k0 < 256; k0 += 64) {
        // stage x tile: coalesced f4 loads
        {
            const int c4 = (tid & 15) * 4;
            const int r0 = tid >> 4;
            #pragma unroll
            for (int p = 0; p < 4; ++p) {
                const int r = r0 + p * 16;
                *(f4*)&xs[r][c4] = *(const f4*)&x[(size_t)(m0 + r) * HID + k0 + c4];
            }
        }
        // stage w tile transposed: thread -> col = tid&63, 16 k values
        {
            const int col = tid & 63;
            const int kb4 = (tid >> 6) * 16;
            #pragma unroll
            for (int kk = 0; kk < 16; kk += 4) {
                f4 v = *(const f4*)&w[(size_t)(n0 + col) * HID + k0 + kb4 + kk];
                wt[kb4 + kk + 0][col] = v[0];
                wt[kb4 + kk + 1][col] = v[1];
                wt[kb4 + kk + 2][col] = v[2];
                wt[kb4 + kk + 3][col] = v[3];
            }
        }
        __syncthreads();

        for (int kk = 0; kk < 64; kk += 4) {
            f4 xv[4], wr[4];
            #pragma unroll
            for (int i = 0; i < 4; ++i) xv[i] = *(const f4*)&xs[ty * 4 + i][kk];
            #pragma unroll
            for (int t = 0; t < 4; ++t) wr[t] = *(const f4*)&wt[kk + t][tx * 4];
            #pragma unroll
            for (int i = 0; i < 4; ++i)
                #pragma unroll
                for (int j = 0; j < 4; ++j)
                    acc[i][j] += xv[i][0] * wr[0][j] + xv[i][1] * wr[1][j]
                               + xv[i][2] * wr[2][j] + xv[i][3] * wr[3][j];
        }
        __syncthreads();
    }

    const f4 bias4 = *(const f4*)&bs[n0 + tx * 4];
    #pragma unroll
    for (int i = 0; i < 4; ++i) {
        const int m = m0 + ty * 4 + i;
        const int bidx = m >> 12;         // / 4096
        const int s = m & 4095;
        #pragma unroll
        for (int j = 0; j < 4; ++j) {
            const int n = n0 + tx * 4 + j;       // 0..255 within projection
            const int hh = n >> 6;
            const int dd = n & 63;
            const float v = acc[i][j] + bias4[j];
            if (proj == 0)
                qb[(((size_t)bidx * NH + hh) * SS + s) * HD + dd] = __float2bfloat16(v);
            else if (proj == 1)
                kb[(((size_t)bidx * NH + hh) * SS + s) * HD + dd] = __float2bfloat16(v);
            else
                vtb[(((size_t)bidx * NH + hh) * HD + dd) * SS + s] = __float2bfloat16(v);
        }
    }
}

// ---------------------------------------------------------------------------
// Flash attention with codon-pair bias.
// grid (64 q-tiles, 8 b*h), block 256 (4 waves x 16 q-rows).
// MFMA 16x16x32 bf16. Online softmax in C/D fragment layout.
// ---------------------------------------------------------------------------
__global__ __launch_bounds__(256)
void attn_kernel(const __hip_bfloat16* __restrict__ qg,
                 const __hip_bfloat16* __restrict__ kg,
                 const __hip_bfloat16* __restrict__ vtg,
                 const int* __restrict__ codons,
                 const float* __restrict__ syn_bias,
                 float* __restrict__ aout)
{
    const int qt = blockIdx.x;
    const int bh = blockIdx.y;
    const int b = bh >> 2, h = bh & 3;
    const int tid = threadIdx.x;
    const int wv = tid >> 6;
    const int lane = tid & 63;
    const int g = lane >> 4;       // 4 lane groups
    const int c16 = lane & 15;

    __shared__ __align__(16) __hip_bfloat16 k_lds[64][72];   // [key][dim] +pad
    __shared__ __align__(16) __hip_bfloat16 vt_lds[64][72];  // [dim][key] +pad
    __shared__ __align__(16) __hip_bfloat16 p_lds[4][16][72];
    __shared__ float bias_lds[4096];
    __shared__ int ck_lds[64];

    // stage syn_bias (64x64 f32) once
    for (int i = tid; i < 4096; i += 256) bias_lds[i] = syn_bias[i];

    // Q fragments (A operand): row = c16, dims (g*8 .. +7) + 32*ks
    const int qrow = qt * 64 + wv * 16 + c16;
    const size_t qoff = ((size_t)(b * NH + h) * SS + qrow) * HD;
    bf8v qf[2];
    qf[0] = *(const bf8v*)&qg[qoff + g * 8];
    qf[1] = *(const bf8v*)&qg[qoff + 32 + g * 8];

    int cq[4];
    #pragma unroll
    for (int r = 0; r < 4; ++r)
        cq[r] = codons[b * SS + qt * 64 + wv * 16 + g * 4 + r];

    float mrow[4], lrow[4], corr[4];
    f4 oacc[4];
    #pragma unroll
    for (int r = 0; r < 4; ++r) { mrow[r] = -1e30f; lrow[r] = 0.f; }
    #pragma unroll
    for (int dt = 0; dt < 4; ++dt) oacc[dt] = (f4){0.f, 0.f, 0.f, 0.f};

    const size_t kbase0 = (size_t)(b * NH + h) * SS * HD;
    const size_t vtbase0 = (size_t)(b * NH + h) * HD * SS;

    for (int kv0 = 0; kv0 < SS; kv0 += 64) {
        // stage K tile [64 keys][64 dims] and V^T tile [64 dims][64 keys]
        for (int i = tid; i < 512; i += 256) {
            const int row = i >> 3, cb = (i & 7) * 8;
            *(u4v*)&k_lds[row][cb]  = *(const u4v*)&kg[kbase0 + (size_t)(kv0 + row) * HD + cb];
            *(u4v*)&vt_lds[row][cb] = *(const u4v*)&vtg[vtbase0 + (size_t)row * SS + kv0 + cb];
        }
        if (tid < 64) ck_lds[tid] = codons[b * SS + kv0 + tid];
        __syncthreads();

        // ---- scores: Q @ K^T -> 16x64 per wave (4 key-tiles x 2 k-steps)
        f4 sacc[4];
        #pragma unroll
        for (int kt = 0; kt < 4; ++kt) sacc[kt] = (f4){0.f, 0.f, 0.f, 0.f};
        #pragma unroll
        for (int ks = 0; ks < 2; ++ks) {
            #pragma unroll
            for (int kt = 0; kt < 4; ++kt) {
                bf8v kf = *(const bf8v*)&k_lds[kt * 16 + c16][ks * 32 + g * 8];
                sacc[kt] = __builtin_amdgcn_mfma_f32_16x16x32_bf16(qf[ks], kf, sacc[kt], 0, 0, 0);
            }
        }

        // ---- scale + codon-pair bias + online softmax
        float sv[4][4];
        #pragma unroll
        for (int kt = 0; kt < 4; ++kt) {
            const int ckk = ck_lds[kt * 16 + c16];
            #pragma unroll
            for (int r = 0; r < 4; ++r)
                sv[kt][r] = sacc[kt][r] * 0.125f + bias_lds[cq[r] * 64 + ckk];
        }
        #pragma unroll
        for (int r = 0; r < 4; ++r) {
            float t = fmaxf(fmaxf(sv[0][r], sv[1][r]), fmaxf(sv[2][r], sv[3][r]));
            #pragma unroll
            for (int msk = 1; msk < 16; msk <<= 1) t = fmaxf(t, __shfl_xor(t, msk, 64));
            const float mn = fmaxf(mrow[r], t);
            corr[r] = __expf(mrow[r] - mn);
            mrow[r] = mn;
            float rs = 0.f;
            #pragma unroll
            for (int kt = 0; kt < 4; ++kt) {
                const float p = __expf(sv[kt][r] - mn);
                sv[kt][r] = p;
                rs += p;
            }
            #pragma unroll
            for (int msk = 1; msk < 16; msk <<= 1) rs += __shfl_xor(rs, msk, 64);
            lrow[r] = lrow[r] * corr[r] + rs;
        }

        // ---- P -> LDS (re-shape into A-fragment layout)
        #pragma unroll
        for (int kt = 0; kt < 4; ++kt)
            #pragma unroll
            for (int r = 0; r < 4; ++r)
                p_lds[wv][g * 4 + r][kt * 16 + c16] = __float2bfloat16(sv[kt][r]);
        asm volatile("s_waitcnt lgkmcnt(0)" ::: "memory");
        __builtin_amdgcn_sched_barrier(0);

        // rescale O accumulator
        #pragma unroll
        for (int dt = 0; dt < 4; ++dt)
            #pragma unroll
            for (int r = 0; r < 4; ++r) oacc[dt][r] *= corr[r];

        // ---- P @ V
        #pragma unroll
        for (int ks = 0; ks < 2; ++ks) {
            bf8v pf = *(const bf8v*)&p_lds[wv][c16][ks * 32 + g * 8];
            #pragma unroll
            for (int dt = 0; dt < 4; ++dt) {
                bf8v vf = *(const bf8v*)&vt_lds[dt * 16 + c16][ks * 32 + g * 8];
                oacc[dt] = __builtin_amdgcn_mfma_f32_16x16x32_bf16(pf, vf, oacc[dt], 0, 0, 0);
            }
        }
        __syncthreads();
    }

    // epilogue: O / l -> attn_out fp32 [b][s][hid]
    #pragma unroll
    for (int dt = 0; dt < 4; ++dt) {
        #pragma unroll
        for (int r = 0; r < 4; ++r) {
            const int srow = qt * 64 + wv * 16 + g * 4 + r;
            const int d = dt * 16 + c16;
            aout[((size_t)b * SS + srow) * HID + h * 64 + d] = oacc[dt][r] / lrow[r];
        }
    }
}

// ---------------------------------------------------------------------------
// Output projection: A(8192x256) @ Wo^T + bo -> out fp32. grid (4, 128).
// ---------------------------------------------------------------------------
__global__ __launch_bounds__(256)
void out_proj_kernel(const float* __restrict__ a, const float* __restrict__ wo,
                     const float* __restrict__ bo, float* __restrict__ out)
{
    const int n0 = blockIdx.x * 64;
    const int m0 = blockIdx.y * 64;

    __shared__ __align__(16) float xs[64][68];
    __shared__ __align__(16) float wt[64][64];

    const int tid = threadIdx.x;
    const int tx = tid & 15, ty = tid >> 4;

    float acc[4][4] = {};

    for (int k0 = 0; k0 < 256; k0 += 64) {
        {
            const int c4 = (tid & 15) * 4;
            const int r0 = tid >> 4;
            #pragma unroll
            for (int p = 0; p < 4; ++p) {
                const int r = r0 + p * 16;
                *(f4*)&xs[r][c4] = *(const f4*)&a[(size_t)(m0 + r) * HID + k0 + c4];
            }
        }
        {
            const int col = tid & 63;
            const int kb4 = (tid >> 6) * 16;
            #pragma unroll
            for (int kk = 0; kk < 16; kk += 4) {
                f4 v = *(const f4*)&wo[(size_t)(n0 + col) * HID + k0 + kb4 + kk];
                wt[kb4 + kk + 0][col] = v[0];
                wt[kb4 + kk + 1][col] = v[1];
                wt[kb4 + kk + 2][col] = v[2];
                wt[kb4 + kk + 3][col] = v[3];
            }
        }
        __syncthreads();

        for (int kk = 0; kk < 64; kk += 4) {
            f4 xv[4], wr[4];
            #pragma unroll
            for (int i = 0; i < 4; ++i) xv[i] = *(const f4*)&xs[ty * 4 + i][kk];
            #pragma unroll
            for (int t = 0; t < 4; ++t) wr[t] = *(const f4*)&wt[kk + t][tx * 4];
            #pragma unroll
            for (int i = 0; i < 4; ++i)
                #pragma unroll
                for (int j = 0; j < 4; ++j)
                    acc[i][j] += xv[i][0] * wr[0][j] + xv[i][1] * wr[1][j]
                               + xv[i][2] * wr[2][j] + xv[i][3] * wr[3][j];
        }
        __syncthreads();
    }

    const f4 bias4 = *(const f4*)&bo[n0 + tx * 4];
    #pragma unroll
    for (int i = 0; i < 4; ++i) {
        const int m = m0 + ty * 4 + i;
        f4 v;
        #pragma unroll
        for (int j = 0; j < 4; ++j) v[j] = acc[i][j] + bias4[j];
        *(f4*)&out[(size_t)m * HID + n0 + tx * 4] = v;
    }
}

extern "C" void kernel_launch(void* const* d_in, const int* in_sizes, int n_in,
                              void* d_out, int out_size, void* d_ws, size_t ws_size,
                              hipStream_t stream)
{
    (void)in_sizes; (void)n_in; (void)out_size; (void)ws_size;
    const float* x        = (const float*)d_in[0];
    const int*   codons   = (const int*)d_in[1];
    const float* syn_bias = (const float*)d_in[2];
    const float* wq = (const float*)d_in[3];
    const float* bq = (const float*)d_in[4];
    const float* wk = (const float*)d_in[5];
    const float* bk = (const float*)d_in[6];
    const float* wv = (const float*)d_in[7];
    const float* bv = (const float*)d_in[8];
    const float* wo = (const float*)d_in[9];
    const float* bo = (const float*)d_in[10];
    float* out = (float*)d_out;

    char* ws = (char*)d_ws;
    __hip_bfloat16* qb  = (__hip_bfloat16*)(ws);
    __hip_bfloat16* kb  = (__hip_bfloat16*)(ws + (size_t)(4u << 20));
    __hip_bfloat16* vtb = (__hip_bfloat16*)(ws + (size_t)(8u << 20));
    float* aout         = (float*)(ws + (size_t)(12u << 20));

    qkv_proj_kernel<<<dim3(12, 128), 256, 0, stream>>>(x, wq, bq, wk, bk, wv, bv, qb, kb, vtb);
    attn_kernel<<<dim3(64, 8), 256, 0, stream>>>(qb, kb, vtb, codons, syn_bias, aout);
    out_proj_kernel<<<dim3(4, 128), 256, 0, stream>>>(aout, wo, bo, out);
}

// Round 2
// 264.004 us; speedup vs baseline: 1.1841x; 1.1841x over previous
//
#include <hip/hip_runtime.h>
#include <hip/hip_bf16.h>

#define NH 4
#define HD 64
#define HID 256
#define BB 2
#define SS 4096

typedef float f4 __attribute__((ext_vector_type(4)));
typedef float f16v __attribute__((ext_vector_type(16)));
typedef short bf8 __attribute__((ext_vector_type(8)));   // 8 bf16 (4 VGPRs)

static __device__ __forceinline__ unsigned pack2(float a, float b) {
    unsigned ua = (unsigned)__bfloat16_as_ushort(__float2bfloat16(a));
    unsigned ub = (unsigned)__bfloat16_as_ushort(__float2bfloat16(b));
    return ua | (ub << 16);
}

// ---------------------------------------------------------------------------
// QKV projection: X(8192x256) @ W^T + b. q pre-scaled by 1/8 (folded softmax
// scale). q,k bf16 [b][h][s][d]; v bf16 TRANSPOSED [b][h][d][s].
// ---------------------------------------------------------------------------
__global__ __launch_bounds__(256)
void qkv_proj_kernel(const float* __restrict__ x,
                     const float* __restrict__ wq, const float* __restrict__ bq,
                     const float* __restrict__ wk, const float* __restrict__ bk,
                     const float* __restrict__ wv, const float* __restrict__ bv,
                     __hip_bfloat16* __restrict__ qb,
                     __hip_bfloat16* __restrict__ kb,
                     __hip_bfloat16* __restrict__ vtb)
{
    const int nt = blockIdx.x;            // 0..11
    const int m0 = blockIdx.y * 64;       // row tile
    const int proj = nt >> 2;             // 0=q 1=k 2=v
    const int n0 = (nt & 3) * 64;         // col within projection
    const float* __restrict__ w  = (proj == 0) ? wq : (proj == 1) ? wk : wv;
    const float* __restrict__ bs = (proj == 0) ? bq : (proj == 1) ? bk : bv;

    __shared__ __align__(16) float xs[64][68];
    __shared__ __align__(16) float wt[64][64];

    const int tid = threadIdx.x;
    const int tx = tid & 15, ty = tid >> 4;

    float acc[4][4] = {};

    for (int k0 = 0; k0 < 256; k0 += 64) {
        {
            const int c4 = (tid & 15) * 4;
            const int r0 = tid >> 4;
            #pragma unroll
            for (int p = 0; p < 4; ++p) {
                const int r = r0 + p * 16;
                *(f4*)&xs[r][c4] = *(const f4*)&x[(size_t)(m0 + r) * HID + k0 + c4];
            }
        }
        {
            const int col = tid & 63;
            const int kb4 = (tid >> 6) * 16;
            #pragma unroll
            for (int kk = 0; kk < 16; kk += 4) {
                f4 v = *(const f4*)&w[(size_t)(n0 + col) * HID + k0 + kb4 + kk];
                wt[kb4 + kk + 0][col] = v[0];
                wt[kb4 + kk + 1][col] = v[1];
                wt[kb4 + kk + 2][col] = v[2];
                wt[kb4 + kk + 3][col] = v[3];
            }
        }
        __syncthreads();

        for (int kk = 0; kk < 64; kk += 4) {
            f4 xv[4], wr[4];
            #pragma unroll
            for (int i = 0; i < 4; ++i) xv[i] = *(const f4*)&xs[ty * 4 + i][kk];
            #pragma unroll
            for (int t = 0; t < 4; ++t) wr[t] = *(const f4*)&wt[kk + t][tx * 4];
            #pragma unroll
            for (int i = 0; i < 4; ++i)
                #pragma unroll
                for (int j = 0; j < 4; ++j)
                    acc[i][j] += xv[i][0] * wr[0][j] + xv[i][1] * wr[1][j]
                               + xv[i][2] * wr[2][j] + xv[i][3] * wr[3][j];
        }
        __syncthreads();
    }

    const f4 bias4 = *(const f4*)&bs[n0 + tx * 4];
    #pragma unroll
    for (int i = 0; i < 4; ++i) {
        const int m = m0 + ty * 4 + i;
        const int bidx = m >> 12;
        const int s = m & 4095;
        #pragma unroll
        for (int j = 0; j < 4; ++j) {
            const int n = n0 + tx * 4 + j;
            const int hh = n >> 6;
            const int dd = n & 63;
            float v = acc[i][j] + bias4[j];
            if (proj == 0) {
                v *= 0.125f;   // fold 1/sqrt(HEAD_DIM) into Q
                qb[(((size_t)bidx * NH + hh) * SS + s) * HD + dd] = __float2bfloat16(v);
            } else if (proj == 1) {
                kb[(((size_t)bidx * NH + hh) * SS + s) * HD + dd] = __float2bfloat16(v);
            } else {
                vtb[(((size_t)bidx * NH + hh) * HD + dd) * SS + s] = __float2bfloat16(v);
            }
        }
    }
}

// ---------------------------------------------------------------------------
// Flash attention, swapped-operand 32x32x16 MFMA structure.
// Block = 256 thr = 4 warps = 2 q-tiles (32 rows) x 2 KV halves (2048 keys).
// grid 512 (bh = bid&7 for XCD L2 locality). LDS = 64KB (2 streams, dbuf).
// ---------------------------------------------------------------------------
__global__ __launch_bounds__(256)
void attn_kernel(const __hip_bfloat16* __restrict__ qg,
                 const __hip_bfloat16* __restrict__ kg,
                 const __hip_bfloat16* __restrict__ vtg,
                 const int* __restrict__ codons,
                 const float* __restrict__ syn_bias,
                 float* __restrict__ aout)
{
    const int bid = blockIdx.x;
    const int bh = bid & 7;
    const int b = bh >> 2, h = bh & 3;
    const int qg64 = bid >> 3;            // 0..63 (64 q-rows per block)
    const int tid = threadIdx.x;
    const int w = tid >> 6;               // warp 0..3
    const int lane = tid & 63;
    const int q5 = lane & 31;
    const int hi = lane >> 5;
    const int qt = w & 1;                 // q-tile within block
    const int half = w >> 1;              // kv half (0: keys 0..2047, 1: 2048..4095)
    const int wl = w & 1;                 // warp index within kv-stream

    __shared__ __align__(16) __hip_bfloat16 k_sh[2][2][64][64];   // [half][buf][key][dim] swizzled
    __shared__ __align__(16) __hip_bfloat16 vt_sh[2][2][64][64];  // [half][buf][dim][key] swizzled

    const size_t kvbase = (size_t)(b * NH + h) * SS * HD;
    const size_t vtbase = (size_t)(b * NH + h) * HD * SS;
    const int qrow = qg64 * 64 + qt * 32 + q5;
    const int cbase = b * SS;

    // ---- Q fragments (B operand; q pre-scaled by 1/8 at projection)
    const size_t qoff = ((size_t)(b * NH + h) * SS + qrow) * HD;
    bf8 qf[4];
    #pragma unroll
    for (int ks = 0; ks < 4; ++ks)
        qf[ks] = *(const bf8*)&qg[qoff + ks * 16 + hi * 8];

    // ---- per-lane synonymy mask for my q-row's codon
    const int cq = codons[cbase + qrow];
    const float beta = syn_bias[cq * 64 + cq];
    unsigned long long mask = 0;
    #pragma unroll
    for (int c4 = 0; c4 < 16; ++c4) {
        f4 mv = *(const f4*)&syn_bias[cq * 64 + c4 * 4];
        #pragma unroll
        for (int j = 0; j < 4; ++j)
            if (mv[j] != 0.0f) mask |= 1ull << (c4 * 4 + j);
    }

    // ---- staging assignment: 2 warps (128 lanes) per stream
    const int il = wl * 64 + lane;        // 0..127
    const int srow = il >> 1;             // key (K) / dim (V)
    const int cpage = (il & 1) * 4;       // 16B-chunk base (0 or 4)

    bf8 gk[4], gv[4];

    auto load_tile = [&](int t) {
        const int kv0 = half * 2048 + t * 64;
        #pragma unroll
        for (int p = 0; p < 4; ++p) {
            const int c = cpage + p;
            gk[p] = *(const bf8*)&kg[kvbase + (size_t)(kv0 + srow) * HD + c * 8];
            gv[p] = *(const bf8*)&vtg[vtbase + (size_t)srow * SS + kv0 + c * 8];
        }
    };
    auto write_tile = [&](int buf) {
        #pragma unroll
        for (int p = 0; p < 4; ++p) {
            const int c = cpage + p;
            const int slot = (c ^ (srow & 7)) * 8;
            *(bf8*)&k_sh[half][buf][srow][slot] = gk[p];
            *(bf8*)&vt_sh[half][buf][srow][slot] = gv[p];
        }
    };

    f16v oacc0, oacc1;
    #pragma unroll
    for (int r = 0; r < 16; ++r) { oacc0[r] = 0.0f; oacc1[r] = 0.0f; }
    float mrun = -1e30f, lrun = 0.0f;

    // prologue: stage tile 0
    load_tile(0);
    write_tile(0);
    __syncthreads();

    for (int t = 0; t < 32; ++t) {
        const int buf = t & 1;
        if (t + 1 < 32) load_tile(t + 1);   // issue early; lands under compute

        // ---- QK^T (swapped): D[key][q], col = q5, row-of-C = key
        bf8 kf0[4], kf1[4];
        #pragma unroll
        for (int ks = 0; ks < 4; ++ks) {
            const int slot = ((ks * 2 + hi) ^ (q5 & 7)) * 8;
            kf0[ks] = *(const bf8*)&k_sh[half][buf][q5][slot];
            kf1[ks] = *(const bf8*)&k_sh[half][buf][32 + q5][slot];
        }
        f16v sA, sB;
        #pragma unroll
        for (int r = 0; r < 16; ++r) { sA[r] = 0.0f; sB[r] = 0.0f; }
        __builtin_amdgcn_s_setprio(1);
        #pragma unroll
        for (int ks = 0; ks < 4; ++ks) {
            sA = __builtin_amdgcn_mfma_f32_32x32x16_bf16(kf0[ks], qf[ks], sA, 0, 0, 0);
            sB = __builtin_amdgcn_mfma_f32_32x32x16_bf16(kf1[ks], qf[ks], sB, 0, 0, 0);
        }
        __builtin_amdgcn_s_setprio(0);

        // ---- add codon-pair bias via mask
        const int kv0 = half * 2048 + t * 64;
        #pragma unroll
        for (int j = 0; j < 4; ++j) {
            const int4 cg0 = *(const int4*)&codons[cbase + kv0 + 8 * j + 4 * hi];
            const int4 cg1 = *(const int4*)&codons[cbase + kv0 + 32 + 8 * j + 4 * hi];
            const int ca[4] = {cg0.x & 63, cg0.y & 63, cg0.z & 63, cg0.w & 63};
            const int cb[4] = {cg1.x & 63, cg1.y & 63, cg1.z & 63, cg1.w & 63};
            #pragma unroll
            for (int i = 0; i < 4; ++i) {
                const int r = j * 4 + i;
                sA[r] += ((mask >> ca[i]) & 1) ? beta : 0.0f;
                sB[r] += ((mask >> cb[i]) & 1) ? beta : 0.0f;
            }
        }

        // ---- online softmax (lane-local + one cross-half exchange)
        float mt = sA[0];
        #pragma unroll
        for (int r = 1; r < 16; ++r) mt = fmaxf(mt, sA[r]);
        #pragma unroll
        for (int r = 0; r < 16; ++r) mt = fmaxf(mt, sB[r]);
        mt = fmaxf(mt, __shfl_xor(mt, 32, 64));
        const float mn = fmaxf(mrun, mt);
        const float corr = __expf(mrun - mn);
        mrun = mn;
        float ls = 0.0f;
        #pragma unroll
        for (int r = 0; r < 16; ++r) { sA[r] = __expf(sA[r] - mn); ls += sA[r]; }
        #pragma unroll
        for (int r = 0; r < 16; ++r) { sB[r] = __expf(sB[r] - mn); ls += sB[r]; }
        ls += __shfl_xor(ls, 32, 64);
        lrun = lrun * corr + ls;
        #pragma unroll
        for (int r = 0; r < 16; ++r) { oacc0[r] *= corr; oacc1[r] *= corr; }

        // ---- P -> bf16 dwords; exchange halves to build PV B-fragments
        unsigned dwv[2][4][2];
        #pragma unroll
        for (int j = 0; j < 4; ++j)
            #pragma unroll
            for (int c = 0; c < 2; ++c) {
                dwv[0][j][c] = pack2(sA[j * 4 + 2 * c], sA[j * 4 + 2 * c + 1]);
                dwv[1][j][c] = pack2(sB[j * 4 + 2 * c], sB[j * 4 + 2 * c + 1]);
            }
        unsigned rc[2][2][2];
        #pragma unroll
        for (int t2 = 0; t2 < 2; ++t2)
            #pragma unroll
            for (int k1 = 0; k1 < 2; ++k1)
                #pragma unroll
                for (int c = 0; c < 2; ++c) {
                    const unsigned snd = hi ? dwv[t2][2 * k1][c] : dwv[t2][2 * k1 + 1][c];
                    rc[t2][k1][c] = (unsigned)__shfl_xor((int)snd, 32, 64);
                }

        // ---- PV: D[d][q], A = V^T frag, B = P frag
        __builtin_amdgcn_s_setprio(1);
        #pragma unroll
        for (int ks = 0; ks < 4; ++ks) {
            const int t2 = ks >> 1, k1 = ks & 1;
            union { unsigned u[4]; bf8 v; } pf;
            pf.u[0] = hi ? rc[t2][k1][0] : dwv[t2][2 * k1][0];
            pf.u[1] = hi ? rc[t2][k1][1] : dwv[t2][2 * k1][1];
            pf.u[2] = hi ? dwv[t2][2 * k1 + 1][0] : rc[t2][k1][0];
            pf.u[3] = hi ? dwv[t2][2 * k1 + 1][1] : rc[t2][k1][1];
            const int slot = ((ks * 2 + hi) ^ (q5 & 7)) * 8;
            const bf8 vf0 = *(const bf8*)&vt_sh[half][buf][q5][slot];
            const bf8 vf1 = *(const bf8*)&vt_sh[half][buf][32 + q5][slot];
            oacc0 = __builtin_amdgcn_mfma_f32_32x32x16_bf16(vf0, pf.v, oacc0, 0, 0, 0);
            oacc1 = __builtin_amdgcn_mfma_f32_32x32x16_bf16(vf1, pf.v, oacc1, 0, 0, 0);
        }
        __builtin_amdgcn_s_setprio(0);

        __syncthreads();
        if (t + 1 < 32) write_tile((t + 1) & 1);
        __syncthreads();
    }

    // ---- merge the two kv-halves (alias k_sh as scratch; loop is done)
    float* o_sh = (float*)&k_sh[0][0][0][0];        // 2 * 32 * 66 floats
    float* ml_p = o_sh + 2 * 32 * 66;               // [qt][{m,l}][q5]
    if (half == 1) {
        #pragma unroll
        for (int dt = 0; dt < 2; ++dt)
            #pragma unroll
            for (int r = 0; r < 16; ++r) {
                const int d = dt * 32 + (r & 3) + 8 * (r >> 2) + 4 * hi;
                o_sh[qt * 2112 + q5 * 66 + d] = dt ? oacc1[r] : oacc0[r];
            }
        if (hi == 0) {
            ml_p[qt * 64 + q5] = mrun;
            ml_p[qt * 64 + 32 + q5] = lrun;
        }
    }
    __syncthreads();
    if (half == 0) {
        const float m1 = ml_p[qt * 64 + q5];
        const float l1 = ml_p[qt * 64 + 32 + q5];
        const float mm = fmaxf(mrun, m1);
        const float a0 = __expf(mrun - mm);
        const float a1 = __expf(m1 - mm);
        const float inv = 1.0f / (lrun * a0 + l1 * a1);
        #pragma unroll
        for (int dt = 0; dt < 2; ++dt)
            #pragma unroll
            for (int r = 0; r < 16; ++r) {
                const int d = dt * 32 + (r & 3) + 8 * (r >> 2) + 4 * hi;
                const float o1 = o_sh[qt * 2112 + q5 * 66 + d];
                const float val = ((dt ? oacc1[r] : oacc0[r]) * a0 + o1 * a1) * inv;
                aout[((size_t)b * SS + qrow) * HID + h * HD + d] = val;
            }
    }
}

// ---------------------------------------------------------------------------
// Output projection: A(8192x256) @ Wo^T + bo -> out fp32. grid (4, 128).
// ---------------------------------------------------------------------------
__global__ __launch_bounds__(256)
void out_proj_kernel(const float* __restrict__ a, const float* __restrict__ wo,
                     const float* __restrict__ bo, float* __restrict__ out)
{
    const int n0 = blockIdx.x * 64;
    const int m0 = blockIdx.y * 64;

    __shared__ __align__(16) float xs[64][68];
    __shared__ __align__(16) float wt[64][64];

    const int tid = threadIdx.x;
    const int tx = tid & 15, ty = tid >> 4;

    float acc[4][4] = {};

    for (int k0 = 0; k0 < 256; k0 += 64) {
        {
            const int c4 = (tid & 15) * 4;
            const int r0 = tid >> 4;
            #pragma unroll
            for (int p = 0; p < 4; ++p) {
                const int r = r0 + p * 16;
                *(f4*)&xs[r][c4] = *(const f4*)&a[(size_t)(m0 + r) * HID + k0 + c4];
            }
        }
        {
            const int col = tid & 63;
            const int kb4 = (tid >> 6) * 16;
            #pragma unroll
            for (int kk = 0; kk < 16; kk += 4) {
                f4 v = *(const f4*)&wo[(size_t)(n0 + col) * HID + k0 + kb4 + kk];
                wt[kb4 + kk + 0][col] = v[0];
                wt[kb4 + kk + 1][col] = v[1];
                wt[kb4 + kk + 2][col] = v[2];
                wt[kb4 + kk + 3][col] = v[3];
            }
        }
        __syncthreads();

        for (int kk = 0; kk < 64; kk += 4) {
            f4 xv[4], wr[4];
            #pragma unroll
            for (int i = 0; i < 4; ++i) xv[i] = *(const f4*)&xs[ty * 4 + i][kk];
            #pragma unroll
            for (int t = 0; t < 4; ++t) wr[t] = *(const f4*)&wt[kk + t][tx * 4];
            #pragma unroll
            for (int i = 0; i < 4; ++i)
                #pragma unroll
                for (int j = 0; j < 4; ++j)
                    acc[i][j] += xv[i][0] * wr[0][j] + xv[i][1] * wr[1][j]
                               + xv[i][2] * wr[2][j] + xv[i][3] * wr[3][j];
        }
        __syncthreads();
    }

    const f4 bias4 = *(const f4*)&bo[n0 + tx * 4];
    #pragma unroll
    for (int i = 0; i < 4; ++i) {
        const int m = m0 + ty * 4 + i;
        f4 v;
        #pragma unroll
        for (int j = 0; j < 4; ++j) v[j] = acc[i][j] + bias4[j];
        *(f4*)&out[(size_t)m * HID + n0 + tx * 4] = v;
    }
}

extern "C" void kernel_launch(void* const* d_in, const int* in_sizes, int n_in,
                              void* d_out, int out_size, void* d_ws, size_t ws_size,
                              hipStream_t stream)
{
    (void)in_sizes; (void)n_in; (void)out_size; (void)ws_size;
    const float* x        = (const float*)d_in[0];
    const int*   codons   = (const int*)d_in[1];
    const float* syn_bias = (const float*)d_in[2];
    const float* wq = (const float*)d_in[3];
    const float* bq = (const float*)d_in[4];
    const float* wk = (const float*)d_in[5];
    const float* bk = (const float*)d_in[6];
    const float* wv = (const float*)d_in[7];
    const float* bv = (const float*)d_in[8];
    const float* wo = (const float*)d_in[9];
    const float* bo = (const float*)d_in[10];
    float* out = (float*)d_out;

    char* ws = (char*)d_ws;
    __hip_bfloat16* qb  = (__hip_bfloat16*)(ws);
    __hip_bfloat16* kb  = (__hip_bfloat16*)(ws + (size_t)(4u << 20));
    __hip_bfloat16* vtb = (__hip_bfloat16*)(ws + (size_t)(8u << 20));
    float* aout         = (float*)(ws + (size_t)(12u << 20));

    qkv_proj_kernel<<<dim3(12, 128), 256, 0, stream>>>(x, wq, bq, wk, bk, wv, bv, qb, kb, vtb);
    attn_kernel<<<512, 256, 0, stream>>>(qb, kb, vtb, codons, syn_bias, aout);
    out_proj_kernel<<<dim3(4, 128), 256, 0, stream>>>(aout, wo, bo, out);
}